// Round 1
// baseline (2264.231 us; speedup 1.0000x reference)
//
#include <hip/hip_runtime.h>
#include <math.h>

#define H40   40
#define NG    120      // 3*H
#define FIN   257
#define KDIM  720      // 80 dims * 9 features (silu + 8 bases)

__device__ __forceinline__ float sigm(float x) { return 1.0f / (1.0f + expf(-x)); }

// Cox-de Boor cubic B-spline bases on uniform grid g[j] = 0.4*(j-3) - 1, j=0..11
__device__ __forceinline__ void bspline8(float x, float* B) {
  float b0[11];
#pragma unroll
  for (int j = 0; j < 11; ++j) {
    float g0 = 0.4f * (float)(j - 3) - 1.0f;
    float g1 = 0.4f * (float)(j - 2) - 1.0f;
    b0[j] = (x >= g0 && x < g1) ? 1.0f : 0.0f;
  }
  float b1[10];
#pragma unroll
  for (int j = 0; j < 10; ++j) {
    float gj  = 0.4f * (float)(j - 3) - 1.0f;
    float gj2 = 0.4f * (float)(j - 1) - 1.0f;   // g[j+2]
    b1[j] = (x - gj) * 2.5f * b0[j] + (gj2 - x) * 2.5f * b0[j + 1];
  }
  float b2[9];
#pragma unroll
  for (int j = 0; j < 9; ++j) {
    float gj  = 0.4f * (float)(j - 3) - 1.0f;
    float gj3 = 0.4f * (float)(j)     - 1.0f;   // g[j+3]
    b2[j] = (x - gj) * 1.25f * b1[j] + (gj3 - x) * 1.25f * b1[j + 1];
  }
#pragma unroll
  for (int j = 0; j < 8; ++j) {
    float gj  = 0.4f * (float)(j - 3) - 1.0f;
    float gj4 = 0.4f * (float)(j + 1) - 1.0f;   // g[j+4]
    B[j] = (x - gj) * (1.0f / 1.2f) * b2[j] + (gj4 - x) * (1.0f / 1.2f) * b2[j + 1];
  }
}

// ---------------------------------------------------------------------------
// prep: Wc[o][i*9+0] = base_w[o][i]; Wc[o][i*9+1+k] = spline_w[o][i][k]*scaler[o][i]
__global__ void prep_wc(const float* __restrict__ base_w, const float* __restrict__ spline_w,
                        const float* __restrict__ scaler, float* __restrict__ Wc, int N, int IN) {
  int idx = blockIdx.x * blockDim.x + threadIdx.x;
  if (idx >= N * IN) return;
  int i = idx % IN;
  int o = idx / IN;
  float sc = scaler[idx];
  float* dst = Wc + (size_t)o * (IN * 9) + i * 9;
  dst[0] = base_w[idx];
#pragma unroll
  for (int k = 0; k < 8; ++k) dst[1 + k] = spline_w[(size_t)idx * 8 + k] * sc;
}

// ---------------------------------------------------------------------------
// Phase A: Gi[M][240] = X[M][257] @ Wcat^T + bias   (cols 0..119 fwd, 120..239 bwd)
__global__ __launch_bounds__(256) void gemm_gi(
    const float* __restrict__ X,
    const float* __restrict__ wih_f0, const float* __restrict__ bih_f0,
    const float* __restrict__ wih_b0, const float* __restrict__ bih_b0,
    float* __restrict__ Gi, int M) {
  __shared__ __align__(16) float Xs[32][68];
  __shared__ __align__(16) float Ws[32][68];
  int tid = threadIdx.x;
  int m0 = blockIdx.x * 64, o0 = blockIdx.y * 64;
  int og = tid & 15, sg = tid >> 4;
  float acc[4][4];
#pragma unroll
  for (int i = 0; i < 4; ++i)
#pragma unroll
    for (int j = 0; j < 4; ++j) acc[i][j] = 0.f;

  for (int ch = 0; ch < 9; ++ch) {
    int k0 = ch * 32;
    for (int idx = tid; idx < 64 * 32; idx += 256) {
      int s = idx >> 5, kk = idx & 31;
      int m = m0 + s, k = k0 + kk;
      Xs[kk][s] = (m < M && k < FIN) ? X[(size_t)m * FIN + k] : 0.f;
    }
    for (int idx = tid; idx < 64 * 32; idx += 256) {
      int o = idx >> 5, kk = idx & 31;
      int oo = o0 + o, k = k0 + kk;
      float w = 0.f;
      if (oo < 240 && k < FIN)
        w = (oo < NG) ? wih_f0[(size_t)oo * FIN + k] : wih_b0[(size_t)(oo - NG) * FIN + k];
      Ws[kk][o] = w;
    }
    __syncthreads();
#pragma unroll
    for (int kk = 0; kk < 32; ++kk) {
      float4 av = *(const float4*)&Xs[kk][sg * 4];
      float4 bv = *(const float4*)&Ws[kk][og * 4];
      float a[4] = {av.x, av.y, av.z, av.w};
      float b[4] = {bv.x, bv.y, bv.z, bv.w};
#pragma unroll
      for (int i = 0; i < 4; ++i)
#pragma unroll
        for (int j = 0; j < 4; ++j) acc[i][j] = fmaf(a[i], b[j], acc[i][j]);
    }
    __syncthreads();
  }
#pragma unroll
  for (int i = 0; i < 4; ++i) {
    int m = m0 + sg * 4 + i;
    if (m >= M) continue;
#pragma unroll
    for (int j = 0; j < 4; ++j) {
      int o = o0 + og * 4 + j;
      if (o >= 240) continue;
      float bias = (o < NG) ? bih_f0[o] : bih_b0[o - NG];
      Gi[(size_t)m * 240 + o] = acc[i][j] + bias;
    }
  }
}

// ---------------------------------------------------------------------------
// Phase B: 128 independent chains (64 batch x 2 dir), weights in registers.
__device__ __forceinline__ float dot40(const float* __restrict__ w, const float* hsh, float bias) {
  float hl[40];
#pragma unroll
  for (int q = 0; q < 10; ++q) {
    float4 v = *(const float4*)(hsh + 4 * q);
    hl[4 * q] = v.x; hl[4 * q + 1] = v.y; hl[4 * q + 2] = v.z; hl[4 * q + 3] = v.w;
  }
  float a0 = bias, a1 = 0.f, a2 = 0.f, a3 = 0.f;
#pragma unroll
  for (int k = 0; k < 40; k += 4) {
    a0 = fmaf(w[k], hl[k], a0);
    a1 = fmaf(w[k + 1], hl[k + 1], a1);
    a2 = fmaf(w[k + 2], hl[k + 2], a2);
    a3 = fmaf(w[k + 3], hl[k + 3], a3);
  }
  return (a0 + a1) + (a2 + a3);
}

__global__ __launch_bounds__(256) void scan_kernel(
    const float* __restrict__ Gi,
    const float* __restrict__ whh0f, const float* __restrict__ bhh0f,
    const float* __restrict__ wih1f, const float* __restrict__ whh1f,
    const float* __restrict__ bih1f, const float* __restrict__ bhh1f,
    const float* __restrict__ whh0b, const float* __restrict__ bhh0b,
    const float* __restrict__ wih1b, const float* __restrict__ whh1b,
    const float* __restrict__ bih1b, const float* __restrict__ bhh1b,
    float* __restrict__ out_cat, int B, int T) {
  int chain = blockIdx.x;
  int d = (chain >= B) ? 1 : 0;
  int b = d ? (chain - B) : chain;
  const float* whh0 = d ? whh0b : whh0f;
  const float* bhh0 = d ? bhh0b : bhh0f;
  const float* wih1 = d ? wih1b : wih1f;
  const float* whh1 = d ? whh1b : whh1f;
  const float* bih1 = d ? bih1b : bih1f;
  const float* bhh1 = d ? bhh1b : bhh1f;

  __shared__ __align__(16) float h0[40];
  __shared__ __align__(16) float h1[40];
  __shared__ float ga[120], gb[40], g1i[120], g1h[120];

  int tid = threadIdx.x;
  float w0[40], w1[40];
  float bias0 = 0.f, bias1 = 0.f;
  if (tid < 120) {
#pragma unroll
    for (int q = 0; q < 10; ++q) {
      float4 v = *(const float4*)&whh0[(size_t)tid * 40 + q * 4];
      w0[4 * q] = v.x; w0[4 * q + 1] = v.y; w0[4 * q + 2] = v.z; w0[4 * q + 3] = v.w;
      float4 u = *(const float4*)&wih1[(size_t)tid * 40 + q * 4];
      w1[4 * q] = u.x; w1[4 * q + 1] = u.y; w1[4 * q + 2] = u.z; w1[4 * q + 3] = u.w;
    }
    bias0 = bhh0[tid];
    bias1 = bih1[tid];
  } else if (tid >= 128 && tid < 248) {
    int o = tid - 128;
#pragma unroll
    for (int q = 0; q < 10; ++q) {
      float4 u = *(const float4*)&whh1[(size_t)o * 40 + q * 4];
      w1[4 * q] = u.x; w1[4 * q + 1] = u.y; w1[4 * q + 2] = u.z; w1[4 * q + 3] = u.w;
    }
    bias1 = bhh1[o];
  }
  if (tid < 40) { h0[tid] = 0.f; h1[tid] = 0.f; }
  __syncthreads();

  const float* gi_base = Gi + (size_t)b * T * 240 + d * NG;
  float gi_cur = 0.f;
  if (tid < 120) gi_cur = gi_base[(size_t)(d ? (T - 1) : 0) * 240 + tid];

  for (int t = 0; t < T; ++t) {
    float gi_next = 0.f;
    if (tid < 120 && t + 1 < T) {
      int tn = d ? (T - 2 - t) : (t + 1);
      gi_next = gi_base[(size_t)tn * 240 + tid];
    }
    // stage A: waves 0-1: gh0 from h0; waves 2-3: gh1 from h1 (uses h1_{t-1})
    if (tid < 120) {
      float acc = dot40(w0, h0, bias0);       // bhh0 + whh0[o]·h0
      float s = gi_cur + acc;
      if (tid < 80) ga[tid] = s;
      else { ga[tid] = gi_cur; gb[tid - 80] = acc; }
    } else if (tid >= 128 && tid < 248) {
      g1h[tid - 128] = dot40(w1, h1, bias1);  // bhh1 + whh1[o]·h1
    }
    __syncthreads();
    // stage B: layer-0 gates -> new h0
    if (tid < 40) {
      float r = sigm(ga[tid]);
      float z = sigm(ga[40 + tid]);
      float n = tanhf(ga[80 + tid] + r * gb[tid]);
      h0[tid] = (1.f - z) * n + z * h0[tid];
    }
    __syncthreads();
    // stage C: gi1 from updated h0
    if (tid < 120) {
      g1i[tid] = dot40(w1, h0, bias1);        // bih1 + wih1[o]·h0new
    }
    __syncthreads();
    // stage D: layer-1 gates -> new h1 -> out
    if (tid < 40) {
      float r = sigm(g1i[tid] + g1h[tid]);
      float z = sigm(g1i[40 + tid] + g1h[40 + tid]);
      float n = tanhf(g1i[80 + tid] + r * g1h[80 + tid]);
      float h = (1.f - z) * n + z * h1[tid];
      h1[tid] = h;
      out_cat[((size_t)b * T + t) * 80 + d * 40 + tid] = h;
    }
    __syncthreads();
    gi_cur = gi_next;
  }
}

// ---------------------------------------------------------------------------
// Phase C: KAN layer as GEMM, K=720 features built on the fly.
template <int FINAL>
__global__ __launch_bounds__(256) void kan_gemm(
    const float* __restrict__ Z, const float* __restrict__ Wc,
    const float* __restrict__ slope, float* __restrict__ Y, int M, int N) {
  __shared__ float Zs[64][81];
  __shared__ __align__(16) float Fs[36][68];
  __shared__ __align__(16) float Ws[36][68];
  int tid = threadIdx.x;
  int m0 = blockIdx.x * 64, o0 = blockIdx.y * 64;
  int og = tid & 15, sg = tid >> 4;
  int szs = tid & 63, dd = tid >> 6;

  for (int idx = tid; idx < 64 * 80; idx += 256) {
    int r = idx / 80, c = idx % 80;
    int m = m0 + r;
    Zs[r][c] = (m < M) ? Z[(size_t)m * 80 + c] : 0.f;
  }
  __syncthreads();

  float acc[4][4];
#pragma unroll
  for (int i = 0; i < 4; ++i)
#pragma unroll
    for (int j = 0; j < 4; ++j) acc[i][j] = 0.f;

  for (int ch = 0; ch < 20; ++ch) {
    {
      float z = Zs[szs][ch * 4 + dd];
      float sil = z / (1.0f + expf(-z));
      float Bv[8];
      bspline8(z, Bv);
      Fs[dd * 9 + 0][szs] = sil;
#pragma unroll
      for (int k = 0; k < 8; ++k) Fs[dd * 9 + 1 + k][szs] = Bv[k];
    }
    for (int idx = tid; idx < 64 * 36; idx += 256) {
      int o = idx / 36, kk = idx % 36;
      int oo = o0 + o;
      Ws[kk][o] = (oo < N) ? Wc[(size_t)oo * KDIM + ch * 36 + kk] : 0.f;
    }
    __syncthreads();
#pragma unroll
    for (int kk = 0; kk < 36; ++kk) {
      float4 av = *(const float4*)&Fs[kk][sg * 4];
      float4 bv = *(const float4*)&Ws[kk][og * 4];
      float a[4] = {av.x, av.y, av.z, av.w};
      float b[4] = {bv.x, bv.y, bv.z, bv.w};
#pragma unroll
      for (int i = 0; i < 4; ++i)
#pragma unroll
        for (int j = 0; j < 4; ++j) acc[i][j] = fmaf(a[i], b[j], acc[i][j]);
    }
    __syncthreads();
  }
#pragma unroll
  for (int i = 0; i < 4; ++i) {
    int m = m0 + sg * 4 + i;
    if (m >= M) continue;
#pragma unroll
    for (int j = 0; j < 4; ++j) {
      int o = o0 + og * 4 + j;
      if (o >= N) continue;
      float y = acc[i][j];
      if (FINAL) y = 1.2f * sigm(slope[o] * y);
      Y[(size_t)m * N + o] = y;
    }
  }
}

// ---------------------------------------------------------------------------
extern "C" void kernel_launch(void* const* d_in, const int* in_sizes, int n_in,
                              void* d_out, int out_size, void* d_ws, size_t ws_size,
                              hipStream_t stream) {
  const float* x        = (const float*)d_in[0];
  const float* wih_f0   = (const float*)d_in[2];
  const float* whh_f0   = (const float*)d_in[3];
  const float* bih_f0   = (const float*)d_in[4];
  const float* bhh_f0   = (const float*)d_in[5];
  const float* wih_f1   = (const float*)d_in[6];
  const float* whh_f1   = (const float*)d_in[7];
  const float* bih_f1   = (const float*)d_in[8];
  const float* bhh_f1   = (const float*)d_in[9];
  const float* wih_b0   = (const float*)d_in[10];
  const float* whh_b0   = (const float*)d_in[11];
  const float* bih_b0   = (const float*)d_in[12];
  const float* bhh_b0   = (const float*)d_in[13];
  const float* wih_b1   = (const float*)d_in[14];
  const float* whh_b1   = (const float*)d_in[15];
  const float* bih_b1   = (const float*)d_in[16];
  const float* bhh_b1   = (const float*)d_in[17];
  const float* gl_base_w   = (const float*)d_in[18];
  const float* gl_spline_w = (const float*)d_in[19];
  const float* gl_scaler   = (const float*)d_in[20];
  const float* lin_base_w   = (const float*)d_in[21];
  const float* lin_spline_w = (const float*)d_in[22];
  const float* lin_scaler   = (const float*)d_in[23];
  const float* slope        = (const float*)d_in[24];

  int B = in_sizes[1];
  int T = in_sizes[0] / (B * FIN);
  int M = B * T;

  // Gi lives in d_out (M*240 <= M*257), overwritten by the final kernel.
  float* Gi = (float*)d_out;
  char* ws = (char*)d_ws;
  size_t off = 0;
  float* cat    = (float*)(ws + off); off += (size_t)M * 80 * 4;
  float* U      = (float*)(ws + off); off += (size_t)M * 80 * 4;
  float* Wc_gl  = (float*)(ws + off); off += (size_t)80 * KDIM * 4;
  float* Wc_lin = (float*)(ws + off); off += (size_t)257 * KDIM * 4;
  (void)ws_size; (void)n_in; (void)out_size;

  prep_wc<<<dim3((80 * 80 + 255) / 256), 256, 0, stream>>>(gl_base_w, gl_spline_w, gl_scaler, Wc_gl, 80, 80);
  prep_wc<<<dim3((257 * 80 + 255) / 256), 256, 0, stream>>>(lin_base_w, lin_spline_w, lin_scaler, Wc_lin, 257, 80);

  gemm_gi<<<dim3((M + 63) / 64, 4), 256, 0, stream>>>(x, wih_f0, bih_f0, wih_b0, bih_b0, Gi, M);

  scan_kernel<<<dim3(2 * B), 256, 0, stream>>>(Gi,
      whh_f0, bhh_f0, wih_f1, whh_f1, bih_f1, bhh_f1,
      whh_b0, bhh_b0, wih_b1, whh_b1, bih_b1, bhh_b1,
      cat, B, T);

  kan_gemm<0><<<dim3((M + 63) / 64, 2), 256, 0, stream>>>(cat, Wc_gl, nullptr, U, M, 80);
  kan_gemm<1><<<dim3((M + 63) / 64, 5), 256, 0, stream>>>(U, Wc_lin, slope, (float*)d_out, M, 257);
}

// Round 2
// 1851.399 us; speedup vs baseline: 1.2230x; 1.2230x over previous
//
#include <hip/hip_runtime.h>
#include <math.h>

#define H40   40
#define NG    120      // 3*H
#define FIN   257
#define KDIM  720      // 80 dims * 9 features (silu + 8 bases)

__device__ __forceinline__ float sigm(float x) { return 1.0f / (1.0f + expf(-x)); }

// Cox-de Boor cubic B-spline bases on uniform grid g[j] = 0.4*(j-3) - 1, j=0..11
__device__ __forceinline__ void bspline8(float x, float* B) {
  float b0[11];
#pragma unroll
  for (int j = 0; j < 11; ++j) {
    float g0 = 0.4f * (float)(j - 3) - 1.0f;
    float g1 = 0.4f * (float)(j - 2) - 1.0f;
    b0[j] = (x >= g0 && x < g1) ? 1.0f : 0.0f;
  }
  float b1[10];
#pragma unroll
  for (int j = 0; j < 10; ++j) {
    float gj  = 0.4f * (float)(j - 3) - 1.0f;
    float gj2 = 0.4f * (float)(j - 1) - 1.0f;   // g[j+2]
    b1[j] = (x - gj) * 2.5f * b0[j] + (gj2 - x) * 2.5f * b0[j + 1];
  }
  float b2[9];
#pragma unroll
  for (int j = 0; j < 9; ++j) {
    float gj  = 0.4f * (float)(j - 3) - 1.0f;
    float gj3 = 0.4f * (float)(j)     - 1.0f;   // g[j+3]
    b2[j] = (x - gj) * 1.25f * b1[j] + (gj3 - x) * 1.25f * b1[j + 1];
  }
#pragma unroll
  for (int j = 0; j < 8; ++j) {
    float gj  = 0.4f * (float)(j - 3) - 1.0f;
    float gj4 = 0.4f * (float)(j + 1) - 1.0f;   // g[j+4]
    B[j] = (x - gj) * (1.0f / 1.2f) * b2[j] + (gj4 - x) * (1.0f / 1.2f) * b2[j + 1];
  }
}

// ---------------------------------------------------------------------------
// prep: Wc[o][i*9+0] = base_w[o][i]; Wc[o][i*9+1+k] = spline_w[o][i][k]*scaler[o][i]
__global__ void prep_wc(const float* __restrict__ base_w, const float* __restrict__ spline_w,
                        const float* __restrict__ scaler, float* __restrict__ Wc, int N, int IN) {
  int idx = blockIdx.x * blockDim.x + threadIdx.x;
  if (idx >= N * IN) return;
  int i = idx % IN;
  int o = idx / IN;
  float sc = scaler[idx];
  float* dst = Wc + (size_t)o * (IN * 9) + i * 9;
  dst[0] = base_w[idx];
#pragma unroll
  for (int k = 0; k < 8; ++k) dst[1 + k] = spline_w[(size_t)idx * 8 + k] * sc;
}

// ---------------------------------------------------------------------------
// Phase A: Gi[M][240] = X[M][257] @ Wcat^T + bias   (cols 0..119 fwd, 120..239 bwd)
__global__ __launch_bounds__(256) void gemm_gi(
    const float* __restrict__ X,
    const float* __restrict__ wih_f0, const float* __restrict__ bih_f0,
    const float* __restrict__ wih_b0, const float* __restrict__ bih_b0,
    float* __restrict__ Gi, int M) {
  __shared__ __align__(16) float Xs[32][68];
  __shared__ __align__(16) float Ws[32][68];
  int tid = threadIdx.x;
  int m0 = blockIdx.x * 64, o0 = blockIdx.y * 64;
  int og = tid & 15, sg = tid >> 4;
  float acc[4][4];
#pragma unroll
  for (int i = 0; i < 4; ++i)
#pragma unroll
    for (int j = 0; j < 4; ++j) acc[i][j] = 0.f;

  for (int ch = 0; ch < 9; ++ch) {
    int k0 = ch * 32;
    for (int idx = tid; idx < 64 * 32; idx += 256) {
      int s = idx >> 5, kk = idx & 31;
      int m = m0 + s, k = k0 + kk;
      Xs[kk][s] = (m < M && k < FIN) ? X[(size_t)m * FIN + k] : 0.f;
    }
    for (int idx = tid; idx < 64 * 32; idx += 256) {
      int o = idx >> 5, kk = idx & 31;
      int oo = o0 + o, k = k0 + kk;
      float w = 0.f;
      if (oo < 240 && k < FIN)
        w = (oo < NG) ? wih_f0[(size_t)oo * FIN + k] : wih_b0[(size_t)(oo - NG) * FIN + k];
      Ws[kk][o] = w;
    }
    __syncthreads();
#pragma unroll
    for (int kk = 0; kk < 32; ++kk) {
      float4 av = *(const float4*)&Xs[kk][sg * 4];
      float4 bv = *(const float4*)&Ws[kk][og * 4];
      float a[4] = {av.x, av.y, av.z, av.w};
      float b[4] = {bv.x, bv.y, bv.z, bv.w};
#pragma unroll
      for (int i = 0; i < 4; ++i)
#pragma unroll
        for (int j = 0; j < 4; ++j) acc[i][j] = fmaf(a[i], b[j], acc[i][j]);
    }
    __syncthreads();
  }
#pragma unroll
  for (int i = 0; i < 4; ++i) {
    int m = m0 + sg * 4 + i;
    if (m >= M) continue;
#pragma unroll
    for (int j = 0; j < 4; ++j) {
      int o = o0 + og * 4 + j;
      if (o >= 240) continue;
      float bias = (o < NG) ? bih_f0[o] : bih_b0[o - NG];
      Gi[(size_t)m * 240 + o] = acc[i][j] + bias;
    }
  }
}

// ---------------------------------------------------------------------------
// Phase B: 128 chains (64 batch x 2 dir), 2 waves per chain, layer-pipelined.
// Wave0: all h0-dots (whh0 rows 0..119 -> s0; wih1 rows 0..119 -> si), L0 update.
// Wave1: h1-dots (whh1 rows 0..119 -> sh), gi prefetch, L1 update (one step late).
__global__ __launch_bounds__(128, 1) void scan_kernel(
    const float* __restrict__ Gi,
    const float* __restrict__ whh0f, const float* __restrict__ bhh0f,
    const float* __restrict__ wih1f, const float* __restrict__ whh1f,
    const float* __restrict__ bih1f, const float* __restrict__ bhh1f,
    const float* __restrict__ whh0b, const float* __restrict__ bhh0b,
    const float* __restrict__ wih1b, const float* __restrict__ whh1b,
    const float* __restrict__ bih1b, const float* __restrict__ bhh1b,
    float* __restrict__ out_cat, int B, int T) {
  int chain = blockIdx.x;
  int dir = (chain >= B) ? 1 : 0;
  int b = chain - dir * B;
  const float* whh0 = dir ? whh0b : whh0f;
  const float* bhh0 = dir ? bhh0b : bhh0f;
  const float* wih1 = dir ? wih1b : wih1f;
  const float* whh1 = dir ? whh1b : whh1f;
  const float* bih1 = dir ? bih1b : bih1f;
  const float* bhh1 = dir ? bhh1b : bhh1f;

  __shared__ __align__(16) float h0buf[40];
  __shared__ __align__(16) float h1buf[40];
  __shared__ float sA[240];          // 0..119: s0 (bhh0 + whh0.h0); 120..239: si (bih1 + wih1.h0)
  __shared__ float sH[120];          // sh (bhh1 + whh1.h1)
  __shared__ __align__(16) float gib[2][120];  // gi ping-pong (iter parity)

  int tid = threadIdx.x;
  int wv = tid >> 6;
  int l = tid & 63;

  // ---- per-lane weights ----
  float w[4][40];
  float bs[4] = {0.f, 0.f, 0.f, 0.f};
  if (wv == 0) {
#pragma unroll
    for (int j = 0; j < 4; ++j) {
      int d = l + 64 * j; d = (d > 239) ? 239 : d;
      const float* wr = (d < 120) ? (whh0 + (size_t)d * 40) : (wih1 + (size_t)(d - 120) * 40);
      bs[j] = (d < 120) ? bhh0[d] : bih1[d - 120];
#pragma unroll
      for (int q = 0; q < 10; ++q) {
        float4 v = *(const float4*)(wr + 4 * q);
        w[j][4 * q] = v.x; w[j][4 * q + 1] = v.y; w[j][4 * q + 2] = v.z; w[j][4 * q + 3] = v.w;
      }
    }
  } else {
#pragma unroll
    for (int j = 0; j < 2; ++j) {
      int d = l + 64 * j; d = (d > 119) ? 119 : d;
      const float* wr = whh1 + (size_t)d * 40;
      bs[j] = bhh1[d];
#pragma unroll
      for (int q = 0; q < 10; ++q) {
        float4 v = *(const float4*)(wr + 4 * q);
        w[j][4 * q] = v.x; w[j][4 * q + 1] = v.y; w[j][4 * q + 2] = v.z; w[j][4 * q + 3] = v.w;
      }
    }
  }

  float hloc = 0.f;   // wave0 lane u<40: h0[u]; wave1 lane u<40: h1[u]
  if (tid < 40) h0buf[tid] = 0.f;
  if (tid >= 64 && tid < 104) h1buf[tid - 64] = 0.f;

  const float* gbase = Gi + (size_t)b * T * 240 + dir * 120;
  float4 giS0 = make_float4(0.f, 0.f, 0.f, 0.f);
  float4 giS1 = make_float4(0.f, 0.f, 0.f, 0.f);
  if (wv == 1 && l < 30) {
    int t0 = dir ? (T - 1) : 0;
    float4 v = *(const float4*)(gbase + (size_t)t0 * 240 + 4 * l);
    *(float4*)&gib[0][4 * l] = v;                    // gi_0 -> LDS parity 0
    if (T > 1) {
      int t1 = dir ? (T - 2) : 1;
      giS1 = *(const float4*)(gbase + (size_t)t1 * 240 + 4 * l);  // gi_1 -> set1
    }
  }
  asm volatile("s_waitcnt lgkmcnt(0)" ::: "memory");
  __builtin_amdgcn_s_barrier();
  __builtin_amdgcn_sched_barrier(0);

  auto body = [&](int k, float4& giLD, float4& giST) {
    // ---------- phase 1: dots + gi issue ----------
    if (wv == 1 && l < 30) {
      int kl = k + 2;
      if (kl <= T - 1) {
        int t = dir ? (T - 1 - kl) : kl;
        giLD = *(const float4*)(gbase + (size_t)t * 240 + 4 * l);
      }
    }
    if (wv == 0) {
      float a0 = bs[0], a1 = bs[1], a2 = bs[2], a3 = bs[3];
#pragma unroll
      for (int q = 0; q < 10; ++q) {
        float4 hv = *(const float4*)&h0buf[4 * q];
        float he[4] = {hv.x, hv.y, hv.z, hv.w};
#pragma unroll
        for (int e = 0; e < 4; ++e) {
          a0 = fmaf(w[0][4 * q + e], he[e], a0);
          a1 = fmaf(w[1][4 * q + e], he[e], a1);
          a2 = fmaf(w[2][4 * q + e], he[e], a2);
          a3 = fmaf(w[3][4 * q + e], he[e], a3);
        }
      }
      sA[l] = a0;
      sA[l + 64] = a1;
      sA[l + 128] = a2;
      if (l < 48) sA[l + 192] = a3;
    } else {
      float a0 = bs[0], a1 = bs[1];
#pragma unroll
      for (int q = 0; q < 10; ++q) {
        float4 hv = *(const float4*)&h1buf[4 * q];
        float he[4] = {hv.x, hv.y, hv.z, hv.w};
#pragma unroll
        for (int e = 0; e < 4; ++e) {
          a0 = fmaf(w[0][4 * q + e], he[e], a0);
          a1 = fmaf(w[1][4 * q + e], he[e], a1);
        }
      }
      sH[l] = a0;
      if (l < 56) sH[l + 64] = a1;
    }
    asm volatile("s_waitcnt lgkmcnt(0)" ::: "memory");
    __builtin_amdgcn_s_barrier();
    __builtin_amdgcn_sched_barrier(0);
    // ---------- phase 2: updates ----------
    if (wv == 0) {
      if (k < T && l < 40) {
        float gr = gib[k & 1][l], gz = gib[k & 1][40 + l], gn = gib[k & 1][80 + l];
        float sr = sA[l], sz = sA[40 + l], sn = sA[80 + l];
        float r = sigm(gr + sr);
        float z = sigm(gz + sz);
        float n = tanhf(gn + r * sn);
        hloc = (1.f - z) * n + z * hloc;
        h0buf[l] = hloc;
      }
    } else {
      if (l < 30 && (k + 1) <= (T - 1)) {
        *(float4*)&gib[(k + 1) & 1][4 * l] = giST;   // stage gi_{k+1}
      }
      if (k >= 1 && l < 40) {
        float ir = sA[120 + l], iz = sA[160 + l], inn = sA[200 + l];
        float hr = sH[l], hz = sH[40 + l], hn = sH[80 + l];
        float r = sigm(ir + hr);
        float z = sigm(iz + hz);
        float n = tanhf(inn + r * hn);
        hloc = (1.f - z) * n + z * hloc;
        h1buf[l] = hloc;
        out_cat[((size_t)b * T + (k - 1)) * 80 + dir * 40 + l] = hloc;
      }
    }
    asm volatile("s_waitcnt lgkmcnt(0)" ::: "memory");
    __builtin_amdgcn_s_barrier();
    __builtin_amdgcn_sched_barrier(0);
  };

  int k = 0;
  while (true) {
    body(k, giS0, giS1); ++k; if (k > T) break;   // even k: load->set0, store<-set1
    body(k, giS1, giS0); ++k; if (k > T) break;   // odd  k: load->set1, store<-set0
  }
}

// ---------------------------------------------------------------------------
// Phase C: KAN layer as GEMM, K=720 features built on the fly.
template <int FINAL>
__global__ __launch_bounds__(256) void kan_gemm(
    const float* __restrict__ Z, const float* __restrict__ Wc,
    const float* __restrict__ slope, float* __restrict__ Y, int M, int N) {
  __shared__ float Zs[64][81];
  __shared__ __align__(16) float Fs[36][68];
  __shared__ __align__(16) float Ws[36][68];
  int tid = threadIdx.x;
  int m0 = blockIdx.x * 64, o0 = blockIdx.y * 64;
  int og = tid & 15, sg = tid >> 4;
  int szs = tid & 63, dd = tid >> 6;

  for (int idx = tid; idx < 64 * 80; idx += 256) {
    int r = idx / 80, c = idx % 80;
    int m = m0 + r;
    Zs[r][c] = (m < M) ? Z[(size_t)m * 80 + c] : 0.f;
  }
  __syncthreads();

  float acc[4][4];
#pragma unroll
  for (int i = 0; i < 4; ++i)
#pragma unroll
    for (int j = 0; j < 4; ++j) acc[i][j] = 0.f;

  for (int ch = 0; ch < 20; ++ch) {
    {
      float z = Zs[szs][ch * 4 + dd];
      float sil = z / (1.0f + expf(-z));
      float Bv[8];
      bspline8(z, Bv);
      Fs[dd * 9 + 0][szs] = sil;
#pragma unroll
      for (int k = 0; k < 8; ++k) Fs[dd * 9 + 1 + k][szs] = Bv[k];
    }
    for (int idx = tid; idx < 64 * 36; idx += 256) {
      int o = idx / 36, kk = idx % 36;
      int oo = o0 + o;
      Ws[kk][o] = (oo < N) ? Wc[(size_t)oo * KDIM + ch * 36 + kk] : 0.f;
    }
    __syncthreads();
#pragma unroll
    for (int kk = 0; kk < 36; ++kk) {
      float4 av = *(const float4*)&Fs[kk][sg * 4];
      float4 bv = *(const float4*)&Ws[kk][og * 4];
      float a[4] = {av.x, av.y, av.z, av.w};
      float b[4] = {bv.x, bv.y, bv.z, bv.w};
#pragma unroll
      for (int i = 0; i < 4; ++i)
#pragma unroll
        for (int j = 0; j < 4; ++j) acc[i][j] = fmaf(a[i], b[j], acc[i][j]);
    }
    __syncthreads();
  }
#pragma unroll
  for (int i = 0; i < 4; ++i) {
    int m = m0 + sg * 4 + i;
    if (m >= M) continue;
#pragma unroll
    for (int j = 0; j < 4; ++j) {
      int o = o0 + og * 4 + j;
      if (o >= N) continue;
      float y = acc[i][j];
      if (FINAL) y = 1.2f * sigm(slope[o] * y);
      Y[(size_t)m * N + o] = y;
    }
  }
}

// ---------------------------------------------------------------------------
extern "C" void kernel_launch(void* const* d_in, const int* in_sizes, int n_in,
                              void* d_out, int out_size, void* d_ws, size_t ws_size,
                              hipStream_t stream) {
  const float* x        = (const float*)d_in[0];
  const float* wih_f0   = (const float*)d_in[2];
  const float* whh_f0   = (const float*)d_in[3];
  const float* bih_f0   = (const float*)d_in[4];
  const float* bhh_f0   = (const float*)d_in[5];
  const float* wih_f1   = (const float*)d_in[6];
  const float* whh_f1   = (const float*)d_in[7];
  const float* bih_f1   = (const float*)d_in[8];
  const float* bhh_f1   = (const float*)d_in[9];
  const float* wih_b0   = (const float*)d_in[10];
  const float* whh_b0   = (const float*)d_in[11];
  const float* bih_b0   = (const float*)d_in[12];
  const float* bhh_b0   = (const float*)d_in[13];
  const float* wih_b1   = (const float*)d_in[14];
  const float* whh_b1   = (const float*)d_in[15];
  const float* bih_b1   = (const float*)d_in[16];
  const float* bhh_b1   = (const float*)d_in[17];
  const float* gl_base_w   = (const float*)d_in[18];
  const float* gl_spline_w = (const float*)d_in[19];
  const float* gl_scaler   = (const float*)d_in[20];
  const float* lin_base_w   = (const float*)d_in[21];
  const float* lin_spline_w = (const float*)d_in[22];
  const float* lin_scaler   = (const float*)d_in[23];
  const float* slope        = (const float*)d_in[24];

  int B = in_sizes[1];
  int T = in_sizes[0] / (B * FIN);
  int M = B * T;

  // Gi lives in d_out (M*240 <= M*257), overwritten by the final kernel.
  float* Gi = (float*)d_out;
  char* ws = (char*)d_ws;
  size_t off = 0;
  float* cat    = (float*)(ws + off); off += (size_t)M * 80 * 4;
  float* U      = (float*)(ws + off); off += (size_t)M * 80 * 4;
  float* Wc_gl  = (float*)(ws + off); off += (size_t)80 * KDIM * 4;
  float* Wc_lin = (float*)(ws + off); off += (size_t)257 * KDIM * 4;
  (void)ws_size; (void)n_in; (void)out_size;

  prep_wc<<<dim3((80 * 80 + 255) / 256), 256, 0, stream>>>(gl_base_w, gl_spline_w, gl_scaler, Wc_gl, 80, 80);
  prep_wc<<<dim3((257 * 80 + 255) / 256), 256, 0, stream>>>(lin_base_w, lin_spline_w, lin_scaler, Wc_lin, 257, 80);

  gemm_gi<<<dim3((M + 63) / 64, 4), 256, 0, stream>>>(x, wih_f0, bih_f0, wih_b0, bih_b0, Gi, M);

  scan_kernel<<<dim3(2 * B), 128, 0, stream>>>(Gi,
      whh_f0, bhh_f0, wih_f1, whh_f1, bih_f1, bhh_f1,
      whh_b0, bhh_b0, wih_b1, whh_b1, bih_b1, bhh_b1,
      cat, B, T);

  kan_gemm<0><<<dim3((M + 63) / 64, 2), 256, 0, stream>>>(cat, Wc_gl, nullptr, U, M, 80);
  kan_gemm<1><<<dim3((M + 63) / 64, 5), 256, 0, stream>>>(U, Wc_lin, slope, (float*)d_out, M, 257);
}

// Round 3
// 1496.693 us; speedup vs baseline: 1.5128x; 1.2370x over previous
//
#include <hip/hip_runtime.h>
#include <math.h>

#define H40   40
#define NG    120      // 3*H
#define FIN   257
#define KDIM  720      // 80 dims * 9 features (silu + 8 bases)

__device__ __forceinline__ float sigm(float x) {
  return __builtin_amdgcn_rcpf(1.0f + __expf(-x));
}
__device__ __forceinline__ float tanh_fast(float x) {
  return 1.0f - 2.0f * __builtin_amdgcn_rcpf(1.0f + __expf(2.0f * x));
}
__device__ __forceinline__ float bcast(float v, int srclane) {
  return __int_as_float(__builtin_amdgcn_ds_bpermute(srclane << 2, __float_as_int(v)));
}

// Cox-de Boor cubic B-spline bases on uniform grid g[j] = 0.4*(j-3) - 1, j=0..11
__device__ __forceinline__ void bspline8(float x, float* B) {
  float b0[11];
#pragma unroll
  for (int j = 0; j < 11; ++j) {
    float g0 = 0.4f * (float)(j - 3) - 1.0f;
    float g1 = 0.4f * (float)(j - 2) - 1.0f;
    b0[j] = (x >= g0 && x < g1) ? 1.0f : 0.0f;
  }
  float b1[10];
#pragma unroll
  for (int j = 0; j < 10; ++j) {
    float gj  = 0.4f * (float)(j - 3) - 1.0f;
    float gj2 = 0.4f * (float)(j - 1) - 1.0f;   // g[j+2]
    b1[j] = (x - gj) * 2.5f * b0[j] + (gj2 - x) * 2.5f * b0[j + 1];
  }
  float b2[9];
#pragma unroll
  for (int j = 0; j < 9; ++j) {
    float gj  = 0.4f * (float)(j - 3) - 1.0f;
    float gj3 = 0.4f * (float)(j)     - 1.0f;   // g[j+3]
    b2[j] = (x - gj) * 1.25f * b1[j] + (gj3 - x) * 1.25f * b1[j + 1];
  }
#pragma unroll
  for (int j = 0; j < 8; ++j) {
    float gj  = 0.4f * (float)(j - 3) - 1.0f;
    float gj4 = 0.4f * (float)(j + 1) - 1.0f;   // g[j+4]
    B[j] = (x - gj) * (1.0f / 1.2f) * b2[j] + (gj4 - x) * (1.0f / 1.2f) * b2[j + 1];
  }
}

// ---------------------------------------------------------------------------
// prep: Wc[o][i*9+0] = base_w[o][i]; Wc[o][i*9+1+k] = spline_w[o][i][k]*scaler[o][i]
__global__ void prep_wc(const float* __restrict__ base_w, const float* __restrict__ spline_w,
                        const float* __restrict__ scaler, float* __restrict__ Wc, int N, int IN) {
  int idx = blockIdx.x * blockDim.x + threadIdx.x;
  if (idx >= N * IN) return;
  int i = idx % IN;
  int o = idx / IN;
  float sc = scaler[idx];
  float* dst = Wc + (size_t)o * (IN * 9) + i * 9;
  dst[0] = base_w[idx];
#pragma unroll
  for (int k = 0; k < 8; ++k) dst[1 + k] = spline_w[(size_t)idx * 8 + k] * sc;
}

// ---------------------------------------------------------------------------
// Phase A: Gi[M][240] = X[M][257] @ Wcat^T + bias   (cols 0..119 fwd, 120..239 bwd)
__global__ __launch_bounds__(256) void gemm_gi(
    const float* __restrict__ X,
    const float* __restrict__ wih_f0, const float* __restrict__ bih_f0,
    const float* __restrict__ wih_b0, const float* __restrict__ bih_b0,
    float* __restrict__ Gi, int M) {
  __shared__ __align__(16) float Xs[32][68];
  __shared__ __align__(16) float Ws[32][68];
  int tid = threadIdx.x;
  int m0 = blockIdx.x * 64, o0 = blockIdx.y * 64;
  int og = tid & 15, sg = tid >> 4;
  float acc[4][4];
#pragma unroll
  for (int i = 0; i < 4; ++i)
#pragma unroll
    for (int j = 0; j < 4; ++j) acc[i][j] = 0.f;

  for (int ch = 0; ch < 9; ++ch) {
    int k0 = ch * 32;
    for (int idx = tid; idx < 64 * 32; idx += 256) {
      int s = idx >> 5, kk = idx & 31;
      int m = m0 + s, k = k0 + kk;
      Xs[kk][s] = (m < M && k < FIN) ? X[(size_t)m * FIN + k] : 0.f;
    }
    for (int idx = tid; idx < 64 * 32; idx += 256) {
      int o = idx >> 5, kk = idx & 31;
      int oo = o0 + o, k = k0 + kk;
      float w = 0.f;
      if (oo < 240 && k < FIN)
        w = (oo < NG) ? wih_f0[(size_t)oo * FIN + k] : wih_b0[(size_t)(oo - NG) * FIN + k];
      Ws[kk][o] = w;
    }
    __syncthreads();
#pragma unroll
    for (int kk = 0; kk < 32; ++kk) {
      float4 av = *(const float4*)&Xs[kk][sg * 4];
      float4 bv = *(const float4*)&Ws[kk][og * 4];
      float a[4] = {av.x, av.y, av.z, av.w};
      float b[4] = {bv.x, bv.y, bv.z, bv.w};
#pragma unroll
      for (int i = 0; i < 4; ++i)
#pragma unroll
        for (int j = 0; j < 4; ++j) acc[i][j] = fmaf(a[i], b[j], acc[i][j]);
    }
    __syncthreads();
  }
#pragma unroll
  for (int i = 0; i < 4; ++i) {
    int m = m0 + sg * 4 + i;
    if (m >= M) continue;
#pragma unroll
    for (int j = 0; j < 4; ++j) {
      int o = o0 + og * 4 + j;
      if (o >= 240) continue;
      float bias = (o < NG) ? bih_f0[o] : bih_b0[o - NG];
      Gi[(size_t)m * 240 + o] = acc[i][j] + bias;
    }
  }
}

// ---------------------------------------------------------------------------
// Phase B: 128 chains, 3 waves/block, ONE barrier per step.
// wave0: layer0 (whh0 dots + update, in-wave gather), gi prefetch in regs.
// wave1: si = bih1 + wih1 . h0   (cross-wave via LDS, double-buffered)
// wave2: layer1 (whh1 dots + update), 2 steps behind wave0.
struct G3 { float r, z, n; };

__global__ __launch_bounds__(192, 1) void scan_kernel(
    const float* __restrict__ Gi,
    const float* __restrict__ whh0f, const float* __restrict__ bhh0f,
    const float* __restrict__ wih1f, const float* __restrict__ whh1f,
    const float* __restrict__ bih1f, const float* __restrict__ bhh1f,
    const float* __restrict__ whh0b, const float* __restrict__ bhh0b,
    const float* __restrict__ wih1b, const float* __restrict__ whh1b,
    const float* __restrict__ bih1b, const float* __restrict__ bhh1b,
    float* __restrict__ out_cat, int B, int T) {
  int chain = blockIdx.x;
  int dir = (chain >= B) ? 1 : 0;
  int b = chain - dir * B;

  const float* whh0 = dir ? whh0b : whh0f;
  const float* bhh0 = dir ? bhh0b : bhh0f;
  const float* wih1 = dir ? wih1b : wih1f;
  const float* whh1 = dir ? whh1b : whh1f;
  const float* bih1 = dir ? bih1b : bih1f;
  const float* bhh1 = dir ? bhh1b : bhh1f;

  __shared__ __align__(16) float h0buf[2][40];
  __shared__ __align__(16) float h1buf[40];
  __shared__ float si[2][120];

  int tid = threadIdx.x;
  int wv = tid >> 6;
  int l = tid & 63;
  int j = l;
  bool upd = (l < 40);

  // per-lane weight rows: o0 = l, o1 = 64+l (valid l<56)
  const float* wsel = (wv == 0) ? whh0 : (wv == 1) ? wih1 : whh1;
  const float* bsel = (wv == 0) ? bhh0 : (wv == 1) ? bih1 : bhh1;
  int r1 = (64 + l < NG) ? (64 + l) : (NG - 1);
  float w0[40], w1[40];
#pragma unroll
  for (int q = 0; q < 10; ++q) {
    float4 v = *(const float4*)(wsel + (size_t)l * 40 + 4 * q);
    w0[4 * q] = v.x; w0[4 * q + 1] = v.y; w0[4 * q + 2] = v.z; w0[4 * q + 3] = v.w;
    float4 u = *(const float4*)(wsel + (size_t)r1 * 40 + 4 * q);
    w1[4 * q] = u.x; w1[4 * q + 1] = u.y; w1[4 * q + 2] = u.z; w1[4 * q + 3] = u.w;
  }
  float b0v = bsel[l], b1v = bsel[r1];

  float hloc = 0.f;                   // wave0: h0[j]; wave2: h1[j]
  if (tid < 40) h0buf[1][tid] = 0.f;  // h0_{-1}
  if (wv == 2 && upd) h1buf[j] = 0.f; // h1_{-1}

  const float* gbase = Gi + (size_t)b * T * 240 + dir * 120;
  G3 gA = {0.f, 0.f, 0.f}, gB = {0.f, 0.f, 0.f};
  if (wv == 0 && upd) {
    int t0 = dir ? (T - 1) : 0;
    const float* p = gbase + (size_t)t0 * 240;
    gA.r = p[j]; gA.z = p[40 + j]; gA.n = p[80 + j];
    if (T > 1) {
      int t1 = dir ? (T - 2) : 1;
      p = gbase + (size_t)t1 * 240;
      gB.r = p[j]; gB.z = p[40 + j]; gB.n = p[80 + j];
    }
  }
  asm volatile("s_waitcnt lgkmcnt(0)" ::: "memory");
  __builtin_amdgcn_s_barrier();
  __builtin_amdgcn_sched_barrier(0);

  auto body = [&](int k, G3& G) {
    if (wv == 0) {
      // consume this step's gi, then immediately re-issue loads for step k+2
      float gr = G.r, gz = G.z, gn = G.n;
      if (upd && (k + 2 <= T - 1)) {
        int t = dir ? (T - 1 - (k + 2)) : (k + 2);
        const float* p = gbase + (size_t)t * 240;
        G.r = p[j]; G.z = p[40 + j]; G.n = p[80 + j];
      }
      if (k <= T - 1) {
        const float4* hb4 = (const float4*)h0buf[(k + 1) & 1];
        float a0 = b0v, a1 = b1v;
#pragma unroll
        for (int q = 0; q < 10; ++q) {
          float4 hv = hb4[q];
          float he[4] = {hv.x, hv.y, hv.z, hv.w};
#pragma unroll
          for (int e = 0; e < 4; ++e) {
            a0 = fmaf(w0[4 * q + e], he[e], a0);
            a1 = fmaf(w1[4 * q + e], he[e], a1);
          }
        }
        // gather r/z/n for this lane's h index j
        float sr  = bcast(a0, j);
        float vz0 = bcast(a0, 40 + j);   // wraps mod 64 for j>=24 (unused then)
        float vz1 = bcast(a1, j - 24);
        float sn  = bcast(a1, 16 + j);
        float sz = (j < 24) ? vz0 : vz1;
        if (upd) {
          float r = sigm(gr + sr);
          float z = sigm(gz + sz);
          float n = tanh_fast(gn + r * sn);
          hloc = (1.f - z) * n + z * hloc;
          h0buf[k & 1][j] = hloc;
        }
      }
    } else if (wv == 1) {
      if (k >= 1 && k <= T) {
        const float4* hb4 = (const float4*)h0buf[(k + 1) & 1];
        float a0 = b0v, a1 = b1v;
#pragma unroll
        for (int q = 0; q < 10; ++q) {
          float4 hv = hb4[q];
          float he[4] = {hv.x, hv.y, hv.z, hv.w};
#pragma unroll
          for (int e = 0; e < 4; ++e) {
            a0 = fmaf(w0[4 * q + e], he[e], a0);
            a1 = fmaf(w1[4 * q + e], he[e], a1);
          }
        }
        float* sp = si[(k - 1) & 1];
        sp[l] = a0;
        if (l < 56) sp[64 + l] = a1;
      }
    } else {
      if (k >= 2 && k <= T + 1) {
        const float4* hb4 = (const float4*)h1buf;
        float a0 = b0v, a1 = b1v;
#pragma unroll
        for (int q = 0; q < 10; ++q) {
          float4 hv = hb4[q];
          float he[4] = {hv.x, hv.y, hv.z, hv.w};
#pragma unroll
          for (int e = 0; e < 4; ++e) {
            a0 = fmaf(w0[4 * q + e], he[e], a0);
            a1 = fmaf(w1[4 * q + e], he[e], a1);
          }
        }
        float sr  = bcast(a0, j);
        float vz0 = bcast(a0, 40 + j);
        float vz1 = bcast(a1, j - 24);
        float sn  = bcast(a1, 16 + j);
        float sz = (j < 24) ? vz0 : vz1;
        if (upd) {
          const float* sp = si[k & 1];
          float ir = sp[j], iz = sp[40 + j], inn = sp[80 + j];
          float r = sigm(ir + sr);
          float z = sigm(iz + sz);
          float n = tanh_fast(inn + r * sn);
          hloc = (1.f - z) * n + z * hloc;
          h1buf[j] = hloc;
          out_cat[((size_t)b * T + (k - 2)) * 80 + dir * 40 + j] = hloc;
        }
      }
    }
    asm volatile("s_waitcnt lgkmcnt(0)" ::: "memory");
    __builtin_amdgcn_s_barrier();
    __builtin_amdgcn_sched_barrier(0);
  };

  int k = 0;
  while (true) {
    body(k, gA); if (++k > T + 1) break;
    body(k, gB); if (++k > T + 1) break;
  }
}

// ---------------------------------------------------------------------------
// Phase C: KAN layer as GEMM, K=720 features built on the fly.
template <int FINAL>
__global__ __launch_bounds__(256) void kan_gemm(
    const float* __restrict__ Z, const float* __restrict__ Wc,
    const float* __restrict__ slope, float* __restrict__ Y, int M, int N) {
  __shared__ float Zs[64][81];
  __shared__ __align__(16) float Fs[36][68];
  __shared__ __align__(16) float Ws[36][68];
  int tid = threadIdx.x;
  int m0 = blockIdx.x * 64, o0 = blockIdx.y * 64;
  int og = tid & 15, sg = tid >> 4;
  int szs = tid & 63, dd = tid >> 6;

  for (int idx = tid; idx < 64 * 80; idx += 256) {
    int r = idx / 80, c = idx % 80;
    int m = m0 + r;
    Zs[r][c] = (m < M) ? Z[(size_t)m * 80 + c] : 0.f;
  }
  __syncthreads();

  float acc[4][4];
#pragma unroll
  for (int i = 0; i < 4; ++i)
#pragma unroll
    for (int j = 0; j < 4; ++j) acc[i][j] = 0.f;

  for (int ch = 0; ch < 20; ++ch) {
    {
      float z = Zs[szs][ch * 4 + dd];
      float sil = z * sigm(z);
      float Bv[8];
      bspline8(z, Bv);
      Fs[dd * 9 + 0][szs] = sil;
#pragma unroll
      for (int k = 0; k < 8; ++k) Fs[dd * 9 + 1 + k][szs] = Bv[k];
    }
    for (int idx = tid; idx < 64 * 36; idx += 256) {
      int o = idx / 36, kk = idx % 36;
      int oo = o0 + o;
      Ws[kk][o] = (oo < N) ? Wc[(size_t)oo * KDIM + ch * 36 + kk] : 0.f;
    }
    __syncthreads();
#pragma unroll
    for (int kk = 0; kk < 36; ++kk) {
      float4 av = *(const float4*)&Fs[kk][sg * 4];
      float4 bv = *(const float4*)&Ws[kk][og * 4];
      float a[4] = {av.x, av.y, av.z, av.w};
      float b[4] = {bv.x, bv.y, bv.z, bv.w};
#pragma unroll
      for (int i = 0; i < 4; ++i)
#pragma unroll
        for (int j = 0; j < 4; ++j) acc[i][j] = fmaf(a[i], b[j], acc[i][j]);
    }
    __syncthreads();
  }
#pragma unroll
  for (int i = 0; i < 4; ++i) {
    int m = m0 + sg * 4 + i;
    if (m >= M) continue;
#pragma unroll
    for (int j = 0; j < 4; ++j) {
      int o = o0 + og * 4 + j;
      if (o >= N) continue;
      float y = acc[i][j];
      if (FINAL) y = 1.2f * sigm(slope[o] * y);
      Y[(size_t)m * N + o] = y;
    }
  }
}

// ---------------------------------------------------------------------------
extern "C" void kernel_launch(void* const* d_in, const int* in_sizes, int n_in,
                              void* d_out, int out_size, void* d_ws, size_t ws_size,
                              hipStream_t stream) {
  const float* x        = (const float*)d_in[0];
  const float* wih_f0   = (const float*)d_in[2];
  const float* whh_f0   = (const float*)d_in[3];
  const float* bih_f0   = (const float*)d_in[4];
  const float* bhh_f0   = (const float*)d_in[5];
  const float* wih_f1   = (const float*)d_in[6];
  const float* whh_f1   = (const float*)d_in[7];
  const float* bih_f1   = (const float*)d_in[8];
  const float* bhh_f1   = (const float*)d_in[9];
  const float* wih_b0   = (const float*)d_in[10];
  const float* whh_b0   = (const float*)d_in[11];
  const float* bih_b0   = (const float*)d_in[12];
  const float* bhh_b0   = (const float*)d_in[13];
  const float* wih_b1   = (const float*)d_in[14];
  const float* whh_b1   = (const float*)d_in[15];
  const float* bih_b1   = (const float*)d_in[16];
  const float* bhh_b1   = (const float*)d_in[17];
  const float* gl_base_w   = (const float*)d_in[18];
  const float* gl_spline_w = (const float*)d_in[19];
  const float* gl_scaler   = (const float*)d_in[20];
  const float* lin_base_w   = (const float*)d_in[21];
  const float* lin_spline_w = (const float*)d_in[22];
  const float* lin_scaler   = (const float*)d_in[23];
  const float* slope        = (const float*)d_in[24];

  int B = in_sizes[1];
  int T = in_sizes[0] / (B * FIN);
  int M = B * T;

  // Gi lives in d_out (M*240 <= M*257), overwritten by the final kernel.
  float* Gi = (float*)d_out;
  char* ws = (char*)d_ws;
  size_t off = 0;
  float* cat    = (float*)(ws + off); off += (size_t)M * 80 * 4;
  float* U      = (float*)(ws + off); off += (size_t)M * 80 * 4;
  float* Wc_gl  = (float*)(ws + off); off += (size_t)80 * KDIM * 4;
  float* Wc_lin = (float*)(ws + off); off += (size_t)257 * KDIM * 4;
  (void)ws_size; (void)n_in; (void)out_size;

  prep_wc<<<dim3((80 * 80 + 255) / 256), 256, 0, stream>>>(gl_base_w, gl_spline_w, gl_scaler, Wc_gl, 80, 80);
  prep_wc<<<dim3((257 * 80 + 255) / 256), 256, 0, stream>>>(lin_base_w, lin_spline_w, lin_scaler, Wc_lin, 257, 80);

  gemm_gi<<<dim3((M + 63) / 64, 4), 256, 0, stream>>>(x, wih_f0, bih_f0, wih_b0, bih_b0, Gi, M);

  scan_kernel<<<dim3(2 * B), 192, 0, stream>>>(Gi,
      whh_f0, bhh_f0, wih_f1, whh_f1, bih_f1, bhh_f1,
      whh_b0, bhh_b0, wih_b1, whh_b1, bih_b1, bhh_b1,
      cat, B, T);

  kan_gemm<0><<<dim3((M + 63) / 64, 2), 256, 0, stream>>>(cat, Wc_gl, nullptr, U, M, 80);
  kan_gemm<1><<<dim3((M + 63) / 64, 5), 256, 0, stream>>>(U, Wc_lin, slope, (float*)d_out, M, 257);
}

// Round 4
// 1127.877 us; speedup vs baseline: 2.0075x; 1.3270x over previous
//
#include <hip/hip_runtime.h>
#include <math.h>

#define H40   40
#define NG    120
#define FIN   257
#define KP    1280     // 80 dims * 16 (silu + 8 splines + 7 pad)
#define KGI   320      // 257 padded to 5*64

typedef float  f4v  __attribute__((ext_vector_type(4)));
typedef short  bfv  __attribute__((ext_vector_type(8)));
typedef unsigned short u8v __attribute__((ext_vector_type(8)));
typedef unsigned short u4v __attribute__((ext_vector_type(4)));

__device__ __forceinline__ float sigm(float x) {
  return __builtin_amdgcn_rcpf(1.0f + __expf(-x));
}
__device__ __forceinline__ float tanh_fast(float x) {
  return 1.0f - 2.0f * __builtin_amdgcn_rcpf(1.0f + __expf(2.0f * x));
}
__device__ __forceinline__ float bcast(float v, int srclane) {
  return __int_as_float(__builtin_amdgcn_ds_bpermute(srclane << 2, __float_as_int(v)));
}
__device__ __forceinline__ unsigned short f2bf(float x) {
  unsigned u = __float_as_uint(x);
  return (unsigned short)((u + 0x7fffu + ((u >> 16) & 1u)) >> 16);
}
__device__ __forceinline__ float bf2f(unsigned short h) {
  return __uint_as_float(((unsigned)h) << 16);
}

// Cox-de Boor cubic B-spline bases on uniform grid g[j] = 0.4*(j-3) - 1
__device__ __forceinline__ void bspline8(float x, float* B) {
  float b0[11];
#pragma unroll
  for (int j = 0; j < 11; ++j) {
    float g0 = 0.4f * (float)(j - 3) - 1.0f;
    float g1 = 0.4f * (float)(j - 2) - 1.0f;
    b0[j] = (x >= g0 && x < g1) ? 1.0f : 0.0f;
  }
  float b1[10];
#pragma unroll
  for (int j = 0; j < 10; ++j) {
    float gj  = 0.4f * (float)(j - 3) - 1.0f;
    float gj2 = 0.4f * (float)(j - 1) - 1.0f;
    b1[j] = (x - gj) * 2.5f * b0[j] + (gj2 - x) * 2.5f * b0[j + 1];
  }
  float b2[9];
#pragma unroll
  for (int j = 0; j < 9; ++j) {
    float gj  = 0.4f * (float)(j - 3) - 1.0f;
    float gj3 = 0.4f * (float)(j)     - 1.0f;
    b2[j] = (x - gj) * 1.25f * b1[j] + (gj3 - x) * 1.25f * b1[j + 1];
  }
#pragma unroll
  for (int j = 0; j < 8; ++j) {
    float gj  = 0.4f * (float)(j - 3) - 1.0f;
    float gj4 = 0.4f * (float)(j + 1) - 1.0f;
    B[j] = (x - gj) * (1.0f / 1.2f) * b2[j] + (gj4 - x) * (1.0f / 1.2f) * b2[j + 1];
  }
}

// ---------------------------------------------------------------------------
// prep: pack KAN weights into hi/lo bf16 planes, k'' = d*16 + f
__global__ void prep_wkan(const float* __restrict__ base_w, const float* __restrict__ spline_w,
                          const float* __restrict__ scaler, unsigned short* __restrict__ Wh,
                          unsigned short* __restrict__ Wl, int N) {
  int idx = blockIdx.x * blockDim.x + threadIdx.x;
  if (idx >= N * 80) return;
  int o = idx / 80, d = idx - o * 80;
  float sc = scaler[idx];
  float vals[16];
  vals[0] = base_w[idx];
#pragma unroll
  for (int k = 0; k < 8; ++k) vals[1 + k] = spline_w[(size_t)idx * 8 + k] * sc;
#pragma unroll
  for (int k = 9; k < 16; ++k) vals[k] = 0.f;
  size_t base = (size_t)o * KP + d * 16;
#pragma unroll
  for (int f = 0; f < 16; ++f) {
    unsigned short h = f2bf(vals[f]);
    Wh[base + f] = h;
    Wl[base + f] = f2bf(vals[f] - bf2f(h));
  }
}

// prep: pack GRU input weights (fwd 0..119, bwd 120..239) into hi/lo planes, K padded 320
__global__ void prep_wgi(const float* __restrict__ wih_f0, const float* __restrict__ wih_b0,
                         unsigned short* __restrict__ Wh, unsigned short* __restrict__ Wl) {
  int idx = blockIdx.x * blockDim.x + threadIdx.x;
  if (idx >= 240 * KGI) return;
  int o = idx / KGI, k = idx - o * KGI;
  float v = 0.f;
  if (k < FIN) v = (o < NG) ? wih_f0[(size_t)o * FIN + k] : wih_b0[(size_t)(o - NG) * FIN + k];
  unsigned short h = f2bf(v);
  Wh[idx] = h;
  Wl[idx] = f2bf(v - bf2f(h));
}

// ---------------------------------------------------------------------------
// Phase A: Gi[M][240] = X[M][257] @ Wcat^T + bih, split-bf16 MFMA. BM=64, BN=128.
__global__ __launch_bounds__(256, 2) void gemm_gi_mfma(
    const float* __restrict__ X, const unsigned short* __restrict__ Wh,
    const unsigned short* __restrict__ Wl,
    const float* __restrict__ bih_f0, const float* __restrict__ bih_b0,
    float* __restrict__ Gi, int M) {
  __shared__ unsigned short Ah[64][72], Al[64][72];
  __shared__ unsigned short Bh[128][72], Bl[128][72];
  int tid = threadIdx.x;
  int m0 = blockIdx.x * 64, o0 = blockIdx.y * 128;
  int wv = tid >> 6, lane = tid & 63;
  int lr = lane & 15, lkq = lane >> 4;

  f4v acc[8];
#pragma unroll
  for (int i = 0; i < 8; ++i) acc[i] = (f4v){0.f, 0.f, 0.f, 0.f};

  for (int c = 0; c < 5; ++c) {
#pragma unroll
    for (int i = 0; i < 4; ++i) {   // A: 64 rows x 16 quad-slots
      int s = tid + i * 256;
      int rr = s >> 4, q = s & 15;
      int m = m0 + rr, k = c * 64 + q * 4;
      float v0 = 0.f, v1 = 0.f, v2 = 0.f, v3 = 0.f;
      if (m < M) {
        const float* xp = X + (size_t)m * FIN;
        if (k < FIN)     v0 = xp[k];
        if (k + 1 < FIN) v1 = xp[k + 1];
        if (k + 2 < FIN) v2 = xp[k + 2];
        if (k + 3 < FIN) v3 = xp[k + 3];
      }
      u4v h, l;
      h[0] = f2bf(v0); l[0] = f2bf(v0 - bf2f(h[0]));
      h[1] = f2bf(v1); l[1] = f2bf(v1 - bf2f(h[1]));
      h[2] = f2bf(v2); l[2] = f2bf(v2 - bf2f(h[2]));
      h[3] = f2bf(v3); l[3] = f2bf(v3 - bf2f(h[3]));
      *(u4v*)&Ah[rr][q * 4] = h;
      *(u4v*)&Al[rr][q * 4] = l;
    }
#pragma unroll
    for (int i = 0; i < 4; ++i) {   // B: 128 cols x 8 oct-slots per plane
      int s = tid + i * 256;
      int col = s >> 3, kq = s & 7;
      int o = o0 + col;
      u8v wh = 0, wl = 0;
      if (o < 240) {
        size_t base = (size_t)o * KGI + c * 64 + kq * 8;
        wh = *(const u8v*)&Wh[base];
        wl = *(const u8v*)&Wl[base];
      }
      *(u8v*)&Bh[col][kq * 8] = wh;
      *(u8v*)&Bl[col][kq * 8] = wl;
    }
    __syncthreads();
#pragma unroll
    for (int s = 0; s < 2; ++s) {
      int kl = s * 32 + lkq * 8;
      bfv a_h = *(const bfv*)&Ah[wv * 16 + lr][kl];
      bfv a_l = *(const bfv*)&Al[wv * 16 + lr][kl];
#pragma unroll
      for (int cf = 0; cf < 8; ++cf) {
        bfv b_h = *(const bfv*)&Bh[cf * 16 + lr][kl];
        bfv b_l = *(const bfv*)&Bl[cf * 16 + lr][kl];
        acc[cf] = __builtin_amdgcn_mfma_f32_16x16x32_bf16(a_h, b_l, acc[cf], 0, 0, 0);
        acc[cf] = __builtin_amdgcn_mfma_f32_16x16x32_bf16(a_l, b_h, acc[cf], 0, 0, 0);
        acc[cf] = __builtin_amdgcn_mfma_f32_16x16x32_bf16(a_h, b_h, acc[cf], 0, 0, 0);
      }
    }
    __syncthreads();
  }
#pragma unroll
  for (int cf = 0; cf < 8; ++cf) {
    int o = o0 + cf * 16 + lr;
    if (o >= 240) continue;
    float bias = (o < NG) ? bih_f0[o] : bih_b0[o - NG];
#pragma unroll
    for (int e = 0; e < 4; ++e) {
      int m = m0 + wv * 16 + lkq * 4 + e;
      if (m < M) Gi[(size_t)m * 240 + o] = acc[cf][e] + bias;
    }
  }
}

// ---------------------------------------------------------------------------
// Phase C: KAN layer, split-bf16 MFMA, features built on the fly. BM=64, BN=64.
template <int FINAL>
__global__ __launch_bounds__(256, 2) void kan_mfma(
    const float* __restrict__ Z, const unsigned short* __restrict__ Wh,
    const unsigned short* __restrict__ Wl, const float* __restrict__ slope,
    float* __restrict__ Y, int M, int N) {
  __shared__ float zst[80 * 64];                 // transposed z tile [d][r]
  __shared__ unsigned short Fh[64][72], Fl[64][72];
  __shared__ unsigned short Bh[64][72], Bl[64][72];
  int tid = threadIdx.x;
  int m0 = blockIdx.x * 64, o0 = blockIdx.y * 64;
  int wv = tid >> 6, lane = tid & 63;
  int lr = lane & 15, lkq = lane >> 4;
  int r = tid & 63, dl = tid >> 6;

#pragma unroll
  for (int i = 0; i < 5; ++i) {                  // 64 rows x 20 float4 slots
    int s = tid + i * 256;
    int rr = s / 20, q = s - rr * 20;
    float4 v = make_float4(0.f, 0.f, 0.f, 0.f);
    int m = m0 + rr;
    if (m < M) v = *(const float4*)&Z[(size_t)m * 80 + q * 4];
    zst[(q * 4 + 0) * 64 + rr] = v.x;
    zst[(q * 4 + 1) * 64 + rr] = v.y;
    zst[(q * 4 + 2) * 64 + rr] = v.z;
    zst[(q * 4 + 3) * 64 + rr] = v.w;
  }
  __syncthreads();

  f4v acc[4];
#pragma unroll
  for (int i = 0; i < 4; ++i) acc[i] = (f4v){0.f, 0.f, 0.f, 0.f};

  for (int c = 0; c < 20; ++c) {
    {
      int d = c * 4 + dl;
      float z = zst[d * 64 + r];
      float f[16];
      f[0] = z * sigm(z);
      bspline8(z, &f[1]);
#pragma unroll
      for (int k = 9; k < 16; ++k) f[k] = 0.f;
      u8v h0, h1, l0, l1;
#pragma unroll
      for (int j = 0; j < 8; ++j) {
        unsigned short hh = f2bf(f[j]);
        h0[j] = hh; l0[j] = f2bf(f[j] - bf2f(hh));
        unsigned short hh2 = f2bf(f[8 + j]);
        h1[j] = hh2; l1[j] = f2bf(f[8 + j] - bf2f(hh2));
      }
      *(u8v*)&Fh[r][dl * 16] = h0;
      *(u8v*)&Fh[r][dl * 16 + 8] = h1;
      *(u8v*)&Fl[r][dl * 16] = l0;
      *(u8v*)&Fl[r][dl * 16 + 8] = l1;
    }
#pragma unroll
    for (int i = 0; i < 2; ++i) {                // W: 64 cols x 8 oct-slots
      int s = tid + i * 256;
      int col = s >> 3, kq = s & 7;
      int o = o0 + col;
      u8v wh = 0, wl = 0;
      if (o < N) {
        size_t base = (size_t)o * KP + c * 64 + kq * 8;
        wh = *(const u8v*)&Wh[base];
        wl = *(const u8v*)&Wl[base];
      }
      *(u8v*)&Bh[col][kq * 8] = wh;
      *(u8v*)&Bl[col][kq * 8] = wl;
    }
    __syncthreads();
#pragma unroll
    for (int s = 0; s < 2; ++s) {
      int kl = s * 32 + lkq * 8;
      bfv a_h = *(const bfv*)&Fh[wv * 16 + lr][kl];
      bfv a_l = *(const bfv*)&Fl[wv * 16 + lr][kl];
#pragma unroll
      for (int cf = 0; cf < 4; ++cf) {
        bfv b_h = *(const bfv*)&Bh[cf * 16 + lr][kl];
        bfv b_l = *(const bfv*)&Bl[cf * 16 + lr][kl];
        acc[cf] = __builtin_amdgcn_mfma_f32_16x16x32_bf16(a_h, b_l, acc[cf], 0, 0, 0);
        acc[cf] = __builtin_amdgcn_mfma_f32_16x16x32_bf16(a_l, b_h, acc[cf], 0, 0, 0);
        acc[cf] = __builtin_amdgcn_mfma_f32_16x16x32_bf16(a_h, b_h, acc[cf], 0, 0, 0);
      }
    }
    __syncthreads();
  }
#pragma unroll
  for (int cf = 0; cf < 4; ++cf) {
    int o = o0 + cf * 16 + lr;
    if (o >= N) continue;
    float sl = FINAL ? slope[o] : 0.f;
#pragma unroll
    for (int e = 0; e < 4; ++e) {
      int m = m0 + wv * 16 + lkq * 4 + e;
      if (m >= M) continue;
      float y = acc[cf][e];
      if (FINAL) y = 1.2f * sigm(sl * y);
      Y[(size_t)m * N + o] = y;
    }
  }
}

// ---------------------------------------------------------------------------
// Phase B: 128 chains, 3 waves/block, ONE barrier per step. (unchanged)
struct G3 { float r, z, n; };

__global__ __launch_bounds__(192, 1) void scan_kernel(
    const float* __restrict__ Gi,
    const float* __restrict__ whh0f, const float* __restrict__ bhh0f,
    const float* __restrict__ wih1f, const float* __restrict__ whh1f,
    const float* __restrict__ bih1f, const float* __restrict__ bhh1f,
    const float* __restrict__ whh0b, const float* __restrict__ bhh0b,
    const float* __restrict__ wih1b, const float* __restrict__ whh1b,
    const float* __restrict__ bih1b, const float* __restrict__ bhh1b,
    float* __restrict__ out_cat, int B, int T) {
  int chain = blockIdx.x;
  int dir = (chain >= B) ? 1 : 0;
  int b = chain - dir * B;

  const float* whh0 = dir ? whh0b : whh0f;
  const float* bhh0 = dir ? bhh0b : bhh0f;
  const float* wih1 = dir ? wih1b : wih1f;
  const float* whh1 = dir ? whh1b : whh1f;
  const float* bih1 = dir ? bih1b : bih1f;
  const float* bhh1 = dir ? bhh1b : bhh1f;

  __shared__ __align__(16) float h0buf[2][40];
  __shared__ __align__(16) float h1buf[40];
  __shared__ float si[2][120];

  int tid = threadIdx.x;
  int wv = tid >> 6;
  int l = tid & 63;
  int j = l;
  bool upd = (l < 40);

  const float* wsel = (wv == 0) ? whh0 : (wv == 1) ? wih1 : whh1;
  const float* bsel = (wv == 0) ? bhh0 : (wv == 1) ? bih1 : bhh1;
  int r1 = (64 + l < NG) ? (64 + l) : (NG - 1);
  float w0[40], w1[40];
#pragma unroll
  for (int q = 0; q < 10; ++q) {
    float4 v = *(const float4*)(wsel + (size_t)l * 40 + 4 * q);
    w0[4 * q] = v.x; w0[4 * q + 1] = v.y; w0[4 * q + 2] = v.z; w0[4 * q + 3] = v.w;
    float4 u = *(const float4*)(wsel + (size_t)r1 * 40 + 4 * q);
    w1[4 * q] = u.x; w1[4 * q + 1] = u.y; w1[4 * q + 2] = u.z; w1[4 * q + 3] = u.w;
  }
  float b0v = bsel[l], b1v = bsel[r1];

  float hloc = 0.f;
  if (tid < 40) h0buf[1][tid] = 0.f;
  if (wv == 2 && upd) h1buf[j] = 0.f;

  const float* gbase = Gi + (size_t)b * T * 240 + dir * 120;
  G3 gA = {0.f, 0.f, 0.f}, gB = {0.f, 0.f, 0.f};
  if (wv == 0 && upd) {
    int t0 = dir ? (T - 1) : 0;
    const float* p = gbase + (size_t)t0 * 240;
    gA.r = p[j]; gA.z = p[40 + j]; gA.n = p[80 + j];
    if (T > 1) {
      int t1 = dir ? (T - 2) : 1;
      p = gbase + (size_t)t1 * 240;
      gB.r = p[j]; gB.z = p[40 + j]; gB.n = p[80 + j];
    }
  }
  asm volatile("s_waitcnt lgkmcnt(0)" ::: "memory");
  __builtin_amdgcn_s_barrier();
  __builtin_amdgcn_sched_barrier(0);

  auto body = [&](int k, G3& G) {
    if (wv == 0) {
      float gr = G.r, gz = G.z, gn = G.n;
      if (upd && (k + 2 <= T - 1)) {
        int t = dir ? (T - 1 - (k + 2)) : (k + 2);
        const float* p = gbase + (size_t)t * 240;
        G.r = p[j]; G.z = p[40 + j]; G.n = p[80 + j];
      }
      if (k <= T - 1) {
        const float4* hb4 = (const float4*)h0buf[(k + 1) & 1];
        float a0 = b0v, a1 = b1v;
#pragma unroll
        for (int q = 0; q < 10; ++q) {
          float4 hv = hb4[q];
          float he[4] = {hv.x, hv.y, hv.z, hv.w};
#pragma unroll
          for (int e = 0; e < 4; ++e) {
            a0 = fmaf(w0[4 * q + e], he[e], a0);
            a1 = fmaf(w1[4 * q + e], he[e], a1);
          }
        }
        float sr  = bcast(a0, j);
        float vz0 = bcast(a0, 40 + j);
        float vz1 = bcast(a1, j - 24);
        float sn  = bcast(a1, 16 + j);
        float sz = (j < 24) ? vz0 : vz1;
        if (upd) {
          float rr = sigm(gr + sr);
          float zz = sigm(gz + sz);
          float nn = tanh_fast(gn + rr * sn);
          hloc = (1.f - zz) * nn + zz * hloc;
          h0buf[k & 1][j] = hloc;
        }
      }
    } else if (wv == 1) {
      if (k >= 1 && k <= T) {
        const float4* hb4 = (const float4*)h0buf[(k + 1) & 1];
        float a0 = b0v, a1 = b1v;
#pragma unroll
        for (int q = 0; q < 10; ++q) {
          float4 hv = hb4[q];
          float he[4] = {hv.x, hv.y, hv.z, hv.w};
#pragma unroll
          for (int e = 0; e < 4; ++e) {
            a0 = fmaf(w0[4 * q + e], he[e], a0);
            a1 = fmaf(w1[4 * q + e], he[e], a1);
          }
        }
        float* sp = si[(k - 1) & 1];
        sp[l] = a0;
        if (l < 56) sp[64 + l] = a1;
      }
    } else {
      if (k >= 2 && k <= T + 1) {
        const float4* hb4 = (const float4*)h1buf;
        float a0 = b0v, a1 = b1v;
#pragma unroll
        for (int q = 0; q < 10; ++q) {
          float4 hv = hb4[q];
          float he[4] = {hv.x, hv.y, hv.z, hv.w};
#pragma unroll
          for (int e = 0; e < 4; ++e) {
            a0 = fmaf(w0[4 * q + e], he[e], a0);
            a1 = fmaf(w1[4 * q + e], he[e], a1);
          }
        }
        float sr  = bcast(a0, j);
        float vz0 = bcast(a0, 40 + j);
        float vz1 = bcast(a1, j - 24);
        float sn  = bcast(a1, 16 + j);
        float sz = (j < 24) ? vz0 : vz1;
        if (upd) {
          const float* sp = si[k & 1];
          float ir = sp[j], iz = sp[40 + j], inn = sp[80 + j];
          float rr = sigm(ir + sr);
          float zz = sigm(iz + sz);
          float nn = tanh_fast(inn + rr * sn);
          hloc = (1.f - zz) * nn + zz * hloc;
          h1buf[j] = hloc;
          out_cat[((size_t)b * T + (k - 2)) * 80 + dir * 40 + j] = hloc;
        }
      }
    }
    asm volatile("s_waitcnt lgkmcnt(0)" ::: "memory");
    __builtin_amdgcn_s_barrier();
    __builtin_amdgcn_sched_barrier(0);
  };

  int k = 0;
  while (true) {
    body(k, gA); if (++k > T + 1) break;
    body(k, gB); if (++k > T + 1) break;
  }
}

// ---------------------------------------------------------------------------
extern "C" void kernel_launch(void* const* d_in, const int* in_sizes, int n_in,
                              void* d_out, int out_size, void* d_ws, size_t ws_size,
                              hipStream_t stream) {
  const float* x        = (const float*)d_in[0];
  const float* wih_f0   = (const float*)d_in[2];
  const float* whh_f0   = (const float*)d_in[3];
  const float* bih_f0   = (const float*)d_in[4];
  const float* bhh_f0   = (const float*)d_in[5];
  const float* wih_f1   = (const float*)d_in[6];
  const float* whh_f1   = (const float*)d_in[7];
  const float* bih_f1   = (const float*)d_in[8];
  const float* bhh_f1   = (const float*)d_in[9];
  const float* wih_b0   = (const float*)d_in[10];
  const float* whh_b0   = (const float*)d_in[11];
  const float* bih_b0   = (const float*)d_in[12];
  const float* bhh_b0   = (const float*)d_in[13];
  const float* wih_b1   = (const float*)d_in[14];
  const float* whh_b1   = (const float*)d_in[15];
  const float* bih_b1   = (const float*)d_in[16];
  const float* bhh_b1   = (const float*)d_in[17];
  const float* gl_base_w   = (const float*)d_in[18];
  const float* gl_spline_w = (const float*)d_in[19];
  const float* gl_scaler   = (const float*)d_in[20];
  const float* lin_base_w   = (const float*)d_in[21];
  const float* lin_spline_w = (const float*)d_in[22];
  const float* lin_scaler   = (const float*)d_in[23];
  const float* slope        = (const float*)d_in[24];

  int B = in_sizes[1];
  int T = in_sizes[0] / (B * FIN);
  int M = B * T;

  float* Gi = (float*)d_out;   // M*240 <= M*257, overwritten by final kernel
  char* ws = (char*)d_ws;
  size_t off = 0;
  float* cat = (float*)(ws + off); off += (size_t)M * 80 * 4;
  float* U   = (float*)(ws + off); off += (size_t)M * 80 * 4;
  unsigned short* Wh_gl  = (unsigned short*)(ws + off); off += (size_t)80 * KP * 2;
  unsigned short* Wl_gl  = (unsigned short*)(ws + off); off += (size_t)80 * KP * 2;
  unsigned short* Wh_lin = (unsigned short*)(ws + off); off += (size_t)FIN * KP * 2;
  unsigned short* Wl_lin = (unsigned short*)(ws + off); off += (size_t)FIN * KP * 2;
  unsigned short* Wh_gi  = (unsigned short*)(ws + off); off += (size_t)240 * KGI * 2;
  unsigned short* Wl_gi  = (unsigned short*)(ws + off); off += (size_t)240 * KGI * 2;
  (void)ws_size; (void)n_in; (void)out_size;

  prep_wkan<<<dim3((80 * 80 + 255) / 256), 256, 0, stream>>>(gl_base_w, gl_spline_w, gl_scaler, Wh_gl, Wl_gl, 80);
  prep_wkan<<<dim3((FIN * 80 + 255) / 256), 256, 0, stream>>>(lin_base_w, lin_spline_w, lin_scaler, Wh_lin, Wl_lin, FIN);
  prep_wgi<<<dim3((240 * KGI + 255) / 256), 256, 0, stream>>>(wih_f0, wih_b0, Wh_gi, Wl_gi);

  gemm_gi_mfma<<<dim3((M + 63) / 64, 2), 256, 0, stream>>>(x, Wh_gi, Wl_gi, bih_f0, bih_b0, Gi, M);

  scan_kernel<<<dim3(2 * B), 192, 0, stream>>>(Gi,
      whh_f0, bhh_f0, wih_f1, whh_f1, bih_f1, bhh_f1,
      whh_b0, bhh_b0, wih_b1, whh_b1, bih_b1, bhh_b1,
      cat, B, T);

  kan_mfma<0><<<dim3((M + 63) / 64, 2), 256, 0, stream>>>(cat, Wh_gl, Wl_gl, nullptr, U, M, 80);
  kan_mfma<1><<<dim3((M + 63) / 64, 5), 256, 0, stream>>>(U, Wh_lin, Wl_lin, slope, (float*)d_out, M, FIN);
}